// Round 11
// baseline (362.792 us; speedup 1.0000x reference)
//
#include <hip/hip_runtime.h>
#include <hip/hip_fp16.h>

#define N_NODES 100000
#define D_FEAT  64
#define N_EDGES 1600000
#define NPB     128                         // nodes per bucket (dst >> 7)
#define NBUCK   ((N_NODES + NPB - 1) / NPB) // 782
#define CAP     3072                        // padded bucket region capacity (mean 2046, sigma~45)
#define CVT_BLOCKS  500                     // 2 blocks/CU; CHUNK 16B-aligned
#define CVT_THREADS 1024
#define CHUNK   (N_EDGES / CVT_BLOCKS)      // 3200 (exact, div by 4)
#define PULL_BLOCKS 2048                    // 8192 waves = device wave capacity
#define SORT_THREADS 512

// ---------- phase 1 fused: X -> fp16 AND atomic-reservation partition (proven r7) ----------
// packed partition word = src | (dst & 127) << 17, weight fp32 in .y
__global__ __launch_bounds__(CVT_THREADS) void cvt_part(const float* __restrict__ X,
                                                        __half* __restrict__ Xh,
                                                        const int* __restrict__ src,
                                                        const int* __restrict__ dst,
                                                        const float* __restrict__ ew,
                                                        int* __restrict__ bcur,
                                                        int2* __restrict__ edges_p) {
    __shared__ int h[NBUCK];                // histogram, then running cursors
    const int t = threadIdx.x;
    for (int i = t; i < NBUCK; i += CVT_THREADS) h[i] = 0;

    const int n4 = N_NODES * D_FEAT / 4;
    for (int i = blockIdx.x * CVT_THREADS + t; i < n4; i += CVT_BLOCKS * CVT_THREADS) {
        float4 v = ((const float4*)X)[i];
        ((__half2*)Xh)[2 * i]     = __floats2half2_rn(v.x, v.y);
        ((__half2*)Xh)[2 * i + 1] = __floats2half2_rn(v.z, v.w);
    }
    __syncthreads();

    const int beg = blockIdx.x * CHUNK;
    const int base = beg + 4 * t;
    const bool act = (4 * t < CHUNK);

    int4 d4;
    if (act) {
        d4 = *(const int4*)(dst + base);
        atomicAdd(&h[d4.x >> 7], 1);
        atomicAdd(&h[d4.y >> 7], 1);
        atomicAdd(&h[d4.z >> 7], 1);
        atomicAdd(&h[d4.w >> 7], 1);
    }
    __syncthreads();

    if (t < NBUCK) {
        int c = h[t];
        h[t] = c ? atomicAdd(&bcur[t], c) : 0;
    }
    __syncthreads();

    if (act) {
        int4   s4 = *(const int4*)(src + base);
        float4 w4 = *(const float4*)(ew + base);
        int b, p;
        b = d4.x >> 7; p = atomicAdd(&h[b], 1);
        if (p < CAP) edges_p[(size_t)b * CAP + p] = make_int2(s4.x | ((d4.x & 127) << 17), __float_as_int(w4.x));
        b = d4.y >> 7; p = atomicAdd(&h[b], 1);
        if (p < CAP) edges_p[(size_t)b * CAP + p] = make_int2(s4.y | ((d4.y & 127) << 17), __float_as_int(w4.y));
        b = d4.z >> 7; p = atomicAdd(&h[b], 1);
        if (p < CAP) edges_p[(size_t)b * CAP + p] = make_int2(s4.z | ((d4.z & 127) << 17), __float_as_int(w4.z));
        b = d4.w >> 7; p = atomicAdd(&h[b], 1);
        if (p < CAP) edges_p[(size_t)b * CAP + p] = make_int2(s4.w | ((d4.w & 127) << 17), __float_as_int(w4.w));
    }
}

// ---------- phase 2: per-bucket counting sort -> sedges {byte_off, fp32 w} (512 thr) ----------
__global__ __launch_bounds__(SORT_THREADS) void sort_bucket(const int2* __restrict__ edges_p,
                                                            const int* __restrict__ bcur,
                                                            int2* __restrict__ sedges,
                                                            int2* __restrict__ nodeptr) {
    __shared__ int cnt[NPB], sc[NPB], cur[NPB];
    __shared__ int2 buf[CAP];
    const int b = blockIdx.x, t = threadIdx.x;
    const int beg = b * CAP;
    int n = bcur[b];
    if (n > CAP) n = CAP;

    if (t < NPB) cnt[t] = 0;
    __syncthreads();
    for (int i = t; i < n; i += SORT_THREADS) {
        int2 e = edges_p[beg + i];
        buf[i] = e;
        atomicAdd(&cnt[e.x >> 17], 1);
    }
    __syncthreads();

    if (t < NPB) sc[t] = cnt[t];
    __syncthreads();
    for (int off = 1; off < NPB; off <<= 1) {
        int v = (t >= off && t < NPB) ? sc[t - off] : 0;
        __syncthreads();
        if (t < NPB) sc[t] += v;
        __syncthreads();
    }
    if (t < NPB) {
        cur[t] = sc[t] - cnt[t];
        int node = b * NPB + t;
        if (node < N_NODES) nodeptr[node] = make_int2(beg + sc[t] - cnt[t], cnt[t]);
    }
    __syncthreads();

    for (int i = t; i < n; i += SORT_THREADS) {
        int2 e = buf[i];
        int p = atomicAdd(&cur[e.x >> 17], 1);
        sedges[beg + p] = make_int2((e.x & 0x1FFFF) << 7, e.y);   // {row byte-offset, fp32 w}
    }
}

// ---------- phase 3: pull SpMM — NODE-PAIR per wave (2x gather MLP) ----------
// Nodes 2i,2i+1 share a bucket -> edges adjacent in sedges. Wave stages both
// into its private 64-slot LDS slice (padded to 16 each, zero-fill pads) and
// interleaves the two gather batches: 16 loads in flight/lane instead of 8.
// Epilogue fully lane-parallel: half 0 writes node A, half 1 writes node B.
// Rare combined-overflow pairs (~0.07%) take the global-path fallback.
template <int MODE>
__global__ __launch_bounds__(256, 8) void spmm_pull(const __half* __restrict__ hprev,
                                                    const int2* __restrict__ nodeptr,
                                                    const int2* __restrict__ edges,
                                                    __half* __restrict__ hout,
                                                    float* __restrict__ out,
                                                    const float* __restrict__ X,
                                                    const __half* __restrict__ h1,
                                                    const __half* __restrict__ h2) {
    __shared__ int2 ebuf[4][64];
    const int t    = threadIdx.x;
    const int wid  = t >> 6;
    const int lane = t & 63;
    const int half = lane >> 5;
    const int sub  = lane & 31;
    const unsigned loff = 4u * sub;           // per-lane byte offset within a row
    const int gw     = blockIdx.x * 4 + wid;
    const int nwaves = gridDim.x * 4;
    const char* hbase = (const char*)hprev;
    const int npairs = N_NODES >> 1;          // N_NODES even

    for (int pr = gw; pr < npairs; pr += nwaves) {
        const int nodeA = pr * 2;
        const int2 npA = nodeptr[nodeA];
        const int2 npB = nodeptr[nodeA + 1];
        const int dA = npA.y, dB = npB.y;
        const int padA = (dA + 15) & ~15;
        const int padB = (dB + 15) & ~15;

        if (padA + padB <= 64) {
            // ---- fused pair path ----
            {
                int2 ev = make_int2(0, 0);
                if (lane < padA) {
                    if (lane < dA) ev = edges[npA.x + lane];
                } else if (lane < padA + padB) {
                    int j = lane - padA;
                    if (j < dB) ev = edges[npB.x + j];
                }
                if (lane < padA + padB) ebuf[wid][lane] = ev;   // pads hold {0,0}
            }
            float axA = 0.f, ayA = 0.f, axB = 0.f, ayB = 0.f;
            const int nbA = padA >> 4, nbB = padB >> 4;
            const int nb = (nbA > nbB) ? nbA : nbB;
            for (int bi = 0; bi < nb; ++bi) {
                unsigned tvA[8], tvB[8];
                float wA[8], wB[8];
                const bool doA = bi < nbA, doB = bi < nbB;      // wave-uniform
                if (doA) {
                    const int baseA = bi * 16 + half;
                    #pragma unroll
                    for (int k = 0; k < 8; ++k) {
                        int2 e = ebuf[wid][baseA + 2 * k];      // ds_read_b64 broadcast
                        wA[k]  = __int_as_float(e.y);
                        tvA[k] = *(const unsigned*)(hbase + ((unsigned)e.x + loff));
                    }
                }
                if (doB) {
                    const int baseB = padA + bi * 16 + half;
                    #pragma unroll
                    for (int k = 0; k < 8; ++k) {
                        int2 e = ebuf[wid][baseB + 2 * k];
                        wB[k]  = __int_as_float(e.y);
                        tvB[k] = *(const unsigned*)(hbase + ((unsigned)e.x + loff));
                    }
                }
                if (doA) {
                    #pragma unroll
                    for (int k = 0; k < 8; ++k) {
                        float2 f = __half22float2(*(__half2*)&tvA[k]);
                        axA += f.x * wA[k];
                        ayA += f.y * wA[k];
                    }
                }
                if (doB) {
                    #pragma unroll
                    for (int k = 0; k < 8; ++k) {
                        float2 f = __half22float2(*(__half2*)&tvB[k]);
                        axB += f.x * wB[k];
                        ayB += f.y * wB[k];
                    }
                }
            }
            axA += __shfl_xor(axA, 32); ayA += __shfl_xor(ayA, 32);
            axB += __shfl_xor(axB, 32); ayB += __shfl_xor(ayB, 32);
            // parallel epilogue: half 0 -> node A, half 1 -> node B
            const int node = nodeA + half;
            const float ax = half ? axB : axA;
            const float ay = half ? ayB : ayA;
            size_t bo = (size_t)node * 32 + sub;
            if (MODE == 2) {
                float2 x  = ((const float2*)X)[bo];
                float2 f1 = __half22float2(((const __half2*)h1)[bo]);
                float2 f2 = __half22float2(((const __half2*)h2)[bo]);
                ((float2*)out)[bo] = make_float2((x.x + f1.x + f2.x + ax) * 0.25f,
                                                 (x.y + f1.y + f2.y + ay) * 0.25f);
            } else {
                ((__half2*)hout)[bo] = __floats2half2_rn(ax, ay);
            }
        } else {
            // ---- rare overflow pair: both nodes via proven global path ----
            #pragma unroll 1
            for (int s = 0; s < 2; ++s) {
                const int node = nodeA + s;
                const int beg = s ? npB.x : npA.x;
                const int d   = s ? dB : dA;
                const int end = beg + d;
                float ax = 0.f, ay = 0.f;
                for (int j = beg; j < end; j += 16) {
                    #pragma unroll
                    for (int k = 0; k < 8; ++k) {
                        int idx = j + 2 * k + half;
                        int2 e = (idx < end) ? edges[idx] : make_int2(0, 0);
                        float wk = __int_as_float(e.y);
                        unsigned tvk = *(const unsigned*)(hbase + ((unsigned)e.x + loff));
                        float2 f = __half22float2(*(__half2*)&tvk);
                        ax += f.x * wk;
                        ay += f.y * wk;
                    }
                }
                ax += __shfl_xor(ax, 32);
                ay += __shfl_xor(ay, 32);
                if (half == 0) {
                    size_t bo = (size_t)node * 32 + sub;
                    if (MODE == 2) {
                        float2 x  = ((const float2*)X)[bo];
                        float2 f1 = __half22float2(((const __half2*)h1)[bo]);
                        float2 f2 = __half22float2(((const __half2*)h2)[bo]);
                        ((float2*)out)[bo] = make_float2((x.x + f1.x + f2.x + ax) * 0.25f,
                                                         (x.y + f1.y + f2.y + ay) * 0.25f);
                    } else {
                        ((__half2*)hout)[bo] = __floats2half2_rn(ax, ay);
                    }
                }
            }
        }
    }
}

extern "C" void kernel_launch(void* const* d_in, const int* in_sizes, int n_in,
                              void* d_out, int out_size, void* d_ws, size_t ws_size,
                              hipStream_t stream) {
    const float* X   = (const float*)d_in[0];
    const int*   src = (const int*)  d_in[1];
    const int*   dst = (const int*)  d_in[2];
    const float* ew  = (const float*)d_in[3];
    float* out = (float*)d_out;

    const size_t feat = (size_t)N_NODES * D_FEAT;

    char* p = (char*)d_ws;
    __half* hA      = (__half*)p; p += feat * sizeof(__half);              // 12.8 MB
    __half* hB      = (__half*)p; p += feat * sizeof(__half);              // 12.8 MB
    __half* Xh      = (__half*)p; p += feat * sizeof(__half);              // 12.8 MB
    int2*  edges_p  = (int2*)p;   p += (size_t)NBUCK * CAP * sizeof(int2); // 19.2 MB padded
    int2*  sedges   = (int2*)p;   p += (size_t)NBUCK * CAP * sizeof(int2); // 19.2 MB
    int2*  nodeptr  = (int2*)p;   p += (size_t)N_NODES * sizeof(int2);     // 0.8 MB
    int*   bcur     = (int*)p;    p += (size_t)NBUCK * 4;

    // async memset replaces the init_bcur kernel (capture-safe; harness uses it too)
    hipMemsetAsync(bcur, 0, (size_t)NBUCK * sizeof(int), stream);

    cvt_part   <<<CVT_BLOCKS, CVT_THREADS, 0, stream>>>(X, Xh, src, dst, ew, bcur, edges_p);
    sort_bucket<<<NBUCK, SORT_THREADS, 0, stream>>>(edges_p, bcur, sedges, nodeptr);

    spmm_pull<0><<<PULL_BLOCKS, 256, 0, stream>>>(Xh, nodeptr, sedges, hA, out, X, hA, hB);
    spmm_pull<1><<<PULL_BLOCKS, 256, 0, stream>>>(hA, nodeptr, sedges, hB, out, X, hA, hB);
    spmm_pull<2><<<PULL_BLOCKS, 256, 0, stream>>>(hB, nodeptr, sedges, (__half*)nullptr, out, X, hA, hB);
}

// Round 12
// 221.203 us; speedup vs baseline: 1.6401x; 1.6401x over previous
//
#include <hip/hip_runtime.h>
#include <hip/hip_fp16.h>

#define N_NODES 100000
#define D_FEAT  64
#define N_EDGES 1600000
#define NPB     128                         // nodes per bucket (dst >> 7)
#define NBUCK   ((N_NODES + NPB - 1) / NPB) // 782
#define CAP     3072                        // padded bucket region capacity (mean 2046, sigma~45)
#define PCAP    4608                        // LDS padded-layout capacity (mean ~3070, >30 sigma)
#define CVT_BLOCKS  500                     // 2 blocks/CU; CHUNK 16B-aligned
#define CVT_THREADS 1024
#define CHUNK   (N_EDGES / CVT_BLOCKS)      // 3200 (exact, div by 4)
#define PULL_BLOCKS 2048                    // 8192 waves
#define WCAP    64                          // per-wave edge stage capacity (max degree ~45)

// ---------- phase 1 fused: X -> fp16 AND atomic-reservation partition (proven r7) ----------
// packed partition word = src | (dst & 127) << 17, weight fp32 in .y
__global__ __launch_bounds__(CVT_THREADS) void cvt_part(const float* __restrict__ X,
                                                        __half* __restrict__ Xh,
                                                        const int* __restrict__ src,
                                                        const int* __restrict__ dst,
                                                        const float* __restrict__ ew,
                                                        int* __restrict__ bcur,
                                                        int2* __restrict__ edges_p) {
    __shared__ int h[NBUCK];                // histogram, then running cursors
    const int t = threadIdx.x;
    for (int i = t; i < NBUCK; i += CVT_THREADS) h[i] = 0;

    const int n4 = N_NODES * D_FEAT / 4;
    for (int i = blockIdx.x * CVT_THREADS + t; i < n4; i += CVT_BLOCKS * CVT_THREADS) {
        float4 v = ((const float4*)X)[i];
        ((__half2*)Xh)[2 * i]     = __floats2half2_rn(v.x, v.y);
        ((__half2*)Xh)[2 * i + 1] = __floats2half2_rn(v.z, v.w);
    }
    __syncthreads();

    const int beg = blockIdx.x * CHUNK;
    const int base = beg + 4 * t;
    const bool act = (4 * t < CHUNK);

    int4 d4;
    if (act) {
        d4 = *(const int4*)(dst + base);
        atomicAdd(&h[d4.x >> 7], 1);
        atomicAdd(&h[d4.y >> 7], 1);
        atomicAdd(&h[d4.z >> 7], 1);
        atomicAdd(&h[d4.w >> 7], 1);
    }
    __syncthreads();

    if (t < NBUCK) {
        int c = h[t];
        h[t] = c ? atomicAdd(&bcur[t], c) : 0;
    }
    __syncthreads();

    if (act) {
        int4   s4 = *(const int4*)(src + base);
        float4 w4 = *(const float4*)(ew + base);
        int b, p;
        b = d4.x >> 7; p = atomicAdd(&h[b], 1);
        if (p < CAP) edges_p[(size_t)b * CAP + p] = make_int2(s4.x | ((d4.x & 127) << 17), __float_as_int(w4.x));
        b = d4.y >> 7; p = atomicAdd(&h[b], 1);
        if (p < CAP) edges_p[(size_t)b * CAP + p] = make_int2(s4.y | ((d4.y & 127) << 17), __float_as_int(w4.y));
        b = d4.z >> 7; p = atomicAdd(&h[b], 1);
        if (p < CAP) edges_p[(size_t)b * CAP + p] = make_int2(s4.z | ((d4.z & 127) << 17), __float_as_int(w4.z));
        b = d4.w >> 7; p = atomicAdd(&h[b], 1);
        if (p < CAP) edges_p[(size_t)b * CAP + p] = make_int2(s4.w | ((d4.w & 127) << 17), __float_as_int(w4.w));
    }
}

// ---------- phase 2 fused: bucket counting sort + LAYER-0 PULL from LDS ----------
// Block = bucket (512 thr = 8 waves). Sorts the bucket's edges into a padded LDS
// layout AND writes sedges {byte_off, fp32 w} + nodeptr for layers 1-2, then the
// 8 waves pull the bucket's 128 nodes from Xh -> hA using the LDS-resident edges
// (no nodeptr loads, no global edge re-read, no launch gap for layer 0).
__global__ __launch_bounds__(512) void sort_pull0(const int2* __restrict__ edges_p,
                                                  const int* __restrict__ bcur,
                                                  int2* __restrict__ sedges,
                                                  int2* __restrict__ nodeptr,
                                                  const __half* __restrict__ Xh,
                                                  __half* __restrict__ hA) {
    __shared__ int cnt[NPB], usc[NPB], psc[NPB], cur[NPB];
    __shared__ int2 sbuf[PCAP];
    __shared__ int fits;
    const int b = blockIdx.x, t = threadIdx.x;
    const int gbeg = b * CAP;
    int n = bcur[b];
    if (n > CAP) n = CAP;

    if (t < NPB) cnt[t] = 0;
    __syncthreads();
    // pass 1: node histogram (edges_p read again in pass 2: L2-warm, 24KB/block)
    for (int i = t; i < n; i += 512)
        atomicAdd(&cnt[edges_p[gbeg + i].x >> 17], 1);
    __syncthreads();

    // dual inclusive scans: unpadded (global layout) and padded-to-16 (LDS layout)
    if (t < NPB) { usc[t] = cnt[t]; psc[t] = (cnt[t] + 15) & ~15; }
    __syncthreads();
    for (int off = 1; off < NPB; off <<= 1) {
        int u = 0, p = 0;
        if (t >= off && t < NPB) { u = usc[t - off]; p = psc[t - off]; }
        __syncthreads();
        if (t < NPB) { usc[t] += u; psc[t] += p; }
        __syncthreads();
    }
    if (t == NPB - 1) fits = (psc[t] <= PCAP);
    if (t < NPB) {
        cur[t] = usc[t] - cnt[t];            // rank base (unpadded exclusive)
        int node = b * NPB + t;
        if (node < N_NODES) nodeptr[node] = make_int2(gbeg + usc[t] - cnt[t], cnt[t]);
    }
    __syncthreads();
    const bool padded = (fits != 0);

    // pass 2: scatter to global sedges (dense) AND LDS sbuf (padded or dense)
    for (int i = t; i < n; i += 512) {
        int2 e = edges_p[gbeg + i];
        int node = e.x >> 17;
        int r = atomicAdd(&cur[node], 1);                  // uoff + rank
        int rank = r - (usc[node] - cnt[node]);
        int2 v = make_int2((e.x & 0x1FFFF) << 7, e.y);     // {row byte-offset, fp32 w}
        sedges[gbeg + r] = v;
        int lb = padded ? (psc[node] - ((cnt[node] + 15) & ~15)) : (usc[node] - cnt[node]);
        sbuf[lb + rank] = v;
    }
    // zero-fill pad gaps (disjoint from scatter slots; 4 threads per node)
    if (padded) {
        int node = t >> 2, j = t & 3;
        int c = cnt[node], pd = (c + 15) & ~15;
        int lb = psc[node] - pd;
        for (int s = c + j; s < pd; s += 4) sbuf[lb + s] = make_int2(0, 0);
    }
    __syncthreads();

    // ---- layer-0 pull: wave wid handles nodes [16*wid, 16*wid+16) of this bucket ----
    const int wid  = t >> 6;
    const int lane = t & 63;
    const int half = lane >> 5;
    const int sub  = lane & 31;
    const unsigned loff = 4u * sub;
    const char* hbase = (const char*)Xh;

    for (int w = 0; w < 16; ++w) {
        const int li = wid * 16 + w;
        const int node = b * NPB + li;
        if (node >= N_NODES) break;                        // wave-uniform
        const int c = cnt[li];
        float ax = 0.f, ay = 0.f;
        if (padded) {
            const int pd = (c + 15) & ~15;
            const int lb = psc[li] - pd;
            const int nb = pd >> 4;
            for (int bi = 0; bi < nb; ++bi) {
                const int base = lb + bi * 16 + half;
                unsigned tv[8]; float wk[8];
                #pragma unroll
                for (int k = 0; k < 8; ++k) {
                    int2 e = sbuf[base + 2 * k];           // ds_read_b64 broadcast
                    wk[k] = __int_as_float(e.y);
                    tv[k] = *(const unsigned*)(hbase + ((unsigned)e.x + loff));
                }
                #pragma unroll
                for (int k = 0; k < 8; ++k) {
                    float2 f = __half22float2(*(__half2*)&tv[k]);
                    ax += f.x * wk[k];
                    ay += f.y * wk[k];
                }
            }
        } else {
            // cold fallback (>30 sigma): dense layout, clamp tail
            const int lb = usc[li] - c;
            for (int j = 0; j < c; j += 16) {
                #pragma unroll
                for (int k = 0; k < 8; ++k) {
                    int idx = j + 2 * k + half;
                    int2 e = (idx < c) ? sbuf[lb + idx] : make_int2(0, 0);
                    float wv = __int_as_float(e.y);
                    unsigned tvk = *(const unsigned*)(hbase + ((unsigned)e.x + loff));
                    float2 f = __half22float2(*(__half2*)&tvk);
                    ax += f.x * wv;
                    ay += f.y * wv;
                }
            }
        }
        ax += __shfl_xor(ax, 32);
        ay += __shfl_xor(ay, 32);
        if (half == 0) {
            size_t bo = (size_t)node * 32 + sub;
            ((__half2*)hA)[bo] = __floats2half2_rn(ax, ay);
        }
    }
}

// ---------- phase 3: pull SpMM layers 1-2 — EXACT proven r7 kernel ----------
template <int MODE>
__global__ __launch_bounds__(256) void spmm_pull(const __half* __restrict__ hprev,
                                                 const int2* __restrict__ nodeptr,
                                                 const int2* __restrict__ edges,
                                                 __half* __restrict__ hout,
                                                 float* __restrict__ out,
                                                 const float* __restrict__ X,
                                                 const __half* __restrict__ h1,
                                                 const __half* __restrict__ h2) {
    __shared__ int2 ebuf[4][WCAP];
    const int t    = threadIdx.x;
    const int wid  = t >> 6;
    const int lane = t & 63;
    const int half = lane >> 5;
    const int sub  = lane & 31;
    const unsigned loff = 4u * sub;           // per-lane byte offset within a row
    const int gw     = blockIdx.x * 4 + wid;
    const int nwaves = gridDim.x * 4;
    const char* hbase = (const char*)hprev;

    for (int node = gw; node < N_NODES; node += nwaves) {
        int2 np = nodeptr[node];
        const int beg = np.x, d = np.y;

        if (d <= WCAP) {
            const int dp = (d + 15) & ~15;    // padded count, <= 64
            if (lane < dp)
                ebuf[wid][lane] = (lane < d) ? edges[beg + lane] : make_int2(0, 0);
            float ax = 0.0f, ay = 0.0f;
            const int nb = dp >> 4;
            for (int bi = 0; bi < nb; ++bi) {
                const int base = bi * 16 + half;      // half 0: even slots, half 1: odd
                unsigned tv[8]; float w[8];
                #pragma unroll
                for (int k = 0; k < 8; ++k) {
                    int2 e = ebuf[wid][base + 2 * k]; // ds_read_b64 broadcast, imm offset
                    w[k]  = __int_as_float(e.y);
                    tv[k] = *(const unsigned*)(hbase + ((unsigned)e.x + loff));
                }
                #pragma unroll
                for (int k = 0; k < 8; ++k) {
                    float2 f = __half22float2(*(__half2*)&tv[k]);
                    ax += f.x * w[k];
                    ay += f.y * w[k];
                }
            }
            ax += __shfl_xor(ax, 32);
            ay += __shfl_xor(ay, 32);
            if (half == 0) {
                size_t bo = (size_t)node * 32 + sub;
                if (MODE == 2) {
                    float2 x  = ((const float2*)X)[bo];
                    float2 f1 = __half22float2(((const __half2*)h1)[bo]);
                    float2 f2 = __half22float2(((const __half2*)h2)[bo]);
                    ((float2*)out)[bo] = make_float2((x.x + f1.x + f2.x + ax) * 0.25f,
                                                     (x.y + f1.y + f2.y + ay) * 0.25f);
                } else {
                    ((__half2*)hout)[bo] = __floats2half2_rn(ax, ay);
                }
            }
        } else {
            // fallback (degree > 64: statistically never) — global path, same math
            const int end = beg + d;
            float ax = 0.0f, ay = 0.0f;
            for (int j = beg; j < end; j += 16) {
                #pragma unroll
                for (int k = 0; k < 8; ++k) {
                    int idx = j + 2 * k + half;
                    int2 e = (idx < end) ? edges[idx] : make_int2(0, 0);
                    float wk = __int_as_float(e.y);
                    unsigned tvk = *(const unsigned*)(hbase + ((unsigned)e.x + loff));
                    float2 f = __half22float2(*(__half2*)&tvk);
                    ax += f.x * wk;
                    ay += f.y * wk;
                }
            }
            ax += __shfl_xor(ax, 32);
            ay += __shfl_xor(ay, 32);
            if (half == 0) {
                size_t bo = (size_t)node * 32 + sub;
                if (MODE == 2) {
                    float2 x  = ((const float2*)X)[bo];
                    float2 f1 = __half22float2(((const __half2*)h1)[bo]);
                    float2 f2 = __half22float2(((const __half2*)h2)[bo]);
                    ((float2*)out)[bo] = make_float2((x.x + f1.x + f2.x + ax) * 0.25f,
                                                     (x.y + f1.y + f2.y + ay) * 0.25f);
                } else {
                    ((__half2*)hout)[bo] = __floats2half2_rn(ax, ay);
                }
            }
        }
    }
}

extern "C" void kernel_launch(void* const* d_in, const int* in_sizes, int n_in,
                              void* d_out, int out_size, void* d_ws, size_t ws_size,
                              hipStream_t stream) {
    const float* X   = (const float*)d_in[0];
    const int*   src = (const int*)  d_in[1];
    const int*   dst = (const int*)  d_in[2];
    const float* ew  = (const float*)d_in[3];
    float* out = (float*)d_out;

    const size_t feat = (size_t)N_NODES * D_FEAT;

    char* p = (char*)d_ws;
    __half* hA      = (__half*)p; p += feat * sizeof(__half);              // 12.8 MB
    __half* hB      = (__half*)p; p += feat * sizeof(__half);              // 12.8 MB
    __half* Xh      = (__half*)p; p += feat * sizeof(__half);              // 12.8 MB
    int2*  edges_p  = (int2*)p;   p += (size_t)NBUCK * CAP * sizeof(int2); // 19.2 MB padded
    int2*  sedges   = (int2*)p;   p += (size_t)NBUCK * CAP * sizeof(int2); // 19.2 MB
    int2*  nodeptr  = (int2*)p;   p += (size_t)N_NODES * sizeof(int2);     // 0.8 MB
    int*   bcur     = (int*)p;    p += (size_t)NBUCK * 4;

    hipMemsetAsync(bcur, 0, (size_t)NBUCK * sizeof(int), stream);

    cvt_part  <<<CVT_BLOCKS, CVT_THREADS, 0, stream>>>(X, Xh, src, dst, ew, bcur, edges_p);
    sort_pull0<<<NBUCK, 512, 0, stream>>>(edges_p, bcur, sedges, nodeptr, Xh, hA);

    spmm_pull<1><<<PULL_BLOCKS, 256, 0, stream>>>(hA, nodeptr, sedges, hB, out, X, hA, hB);
    spmm_pull<2><<<PULL_BLOCKS, 256, 0, stream>>>(hB, nodeptr, sedges, (__half*)nullptr, out, X, hA, hB);
}

// Round 13
// 218.129 us; speedup vs baseline: 1.6632x; 1.0141x over previous
//
#include <hip/hip_runtime.h>
#include <hip/hip_fp16.h>

#define N_NODES 100000
#define D_FEAT  64
#define N_EDGES 1600000
#define NPB     128                         // nodes per bucket (dst >> 7)
#define NBUCK   ((N_NODES + NPB - 1) / NPB) // 782
#define CAP     3072                        // padded bucket region capacity (mean 2046, sigma~45)
#define CVT_BLOCKS  500                     // 2 blocks/CU; CHUNK 16B-aligned
#define CVT_THREADS 1024
#define CHUNK   (N_EDGES / CVT_BLOCKS)      // 3200 (exact, div by 4)
#define PULL_BLOCKS 2048                    // 8192 waves = device wave capacity
#define WCAP    64                          // per-wave edge stage capacity (max degree ~45)
#define SORT_THREADS 512

// ---------- phase 1 fused: X -> fp16 AND atomic-reservation partition (proven r7) ----------
// packed partition word = src | (dst & 127) << 17, weight fp32 in .y
__global__ __launch_bounds__(CVT_THREADS) void cvt_part(const float* __restrict__ X,
                                                        __half* __restrict__ Xh,
                                                        const int* __restrict__ src,
                                                        const int* __restrict__ dst,
                                                        const float* __restrict__ ew,
                                                        int* __restrict__ bcur,
                                                        int2* __restrict__ edges_p) {
    __shared__ int h[NBUCK];                // histogram, then running cursors
    const int t = threadIdx.x;
    for (int i = t; i < NBUCK; i += CVT_THREADS) h[i] = 0;

    const int n4 = N_NODES * D_FEAT / 4;
    for (int i = blockIdx.x * CVT_THREADS + t; i < n4; i += CVT_BLOCKS * CVT_THREADS) {
        float4 v = ((const float4*)X)[i];
        ((__half2*)Xh)[2 * i]     = __floats2half2_rn(v.x, v.y);
        ((__half2*)Xh)[2 * i + 1] = __floats2half2_rn(v.z, v.w);
    }
    __syncthreads();

    const int beg = blockIdx.x * CHUNK;
    const int base = beg + 4 * t;
    const bool act = (4 * t < CHUNK);

    int4 d4;
    if (act) {
        d4 = *(const int4*)(dst + base);
        atomicAdd(&h[d4.x >> 7], 1);
        atomicAdd(&h[d4.y >> 7], 1);
        atomicAdd(&h[d4.z >> 7], 1);
        atomicAdd(&h[d4.w >> 7], 1);
    }
    __syncthreads();

    if (t < NBUCK) {
        int c = h[t];
        h[t] = c ? atomicAdd(&bcur[t], c) : 0;
    }
    __syncthreads();

    if (act) {
        int4   s4 = *(const int4*)(src + base);
        float4 w4 = *(const float4*)(ew + base);
        int b, p;
        b = d4.x >> 7; p = atomicAdd(&h[b], 1);
        if (p < CAP) edges_p[(size_t)b * CAP + p] = make_int2(s4.x | ((d4.x & 127) << 17), __float_as_int(w4.x));
        b = d4.y >> 7; p = atomicAdd(&h[b], 1);
        if (p < CAP) edges_p[(size_t)b * CAP + p] = make_int2(s4.y | ((d4.y & 127) << 17), __float_as_int(w4.y));
        b = d4.z >> 7; p = atomicAdd(&h[b], 1);
        if (p < CAP) edges_p[(size_t)b * CAP + p] = make_int2(s4.z | ((d4.z & 127) << 17), __float_as_int(w4.z));
        b = d4.w >> 7; p = atomicAdd(&h[b], 1);
        if (p < CAP) edges_p[(size_t)b * CAP + p] = make_int2(s4.w | ((d4.w & 127) << 17), __float_as_int(w4.w));
    }
}

// ---------- phase 2: per-bucket counting sort, IN PLACE (proven r5 hazard-free) ----------
// Stages the bucket fully into LDS, then writes back transformed {byte_off, fp32 w}
// into the SAME region (L2-warm lines; no second 19.2 MB buffer).
__global__ __launch_bounds__(SORT_THREADS) void sort_bucket(int2* __restrict__ edges_p,
                                                            const int* __restrict__ bcur,
                                                            int2* __restrict__ nodeptr) {
    __shared__ int cnt[NPB], sc[NPB], cur[NPB];
    __shared__ int2 buf[CAP];
    const int b = blockIdx.x, t = threadIdx.x;
    const int beg = b * CAP;
    int n = bcur[b];
    if (n > CAP) n = CAP;

    if (t < NPB) cnt[t] = 0;
    __syncthreads();
    for (int i = t; i < n; i += SORT_THREADS) {
        int2 e = edges_p[beg + i];
        buf[i] = e;
        atomicAdd(&cnt[e.x >> 17], 1);
    }
    __syncthreads();

    if (t < NPB) sc[t] = cnt[t];
    __syncthreads();
    for (int off = 1; off < NPB; off <<= 1) {
        int v = (t >= off && t < NPB) ? sc[t - off] : 0;
        __syncthreads();
        if (t < NPB) sc[t] += v;
        __syncthreads();
    }
    if (t < NPB) {
        cur[t] = sc[t] - cnt[t];
        int node = b * NPB + t;
        if (node < N_NODES) nodeptr[node] = make_int2(beg + sc[t] - cnt[t], cnt[t]);
    }
    __syncthreads();

    for (int i = t; i < n; i += SORT_THREADS) {
        int2 e = buf[i];
        int p = atomicAdd(&cur[e.x >> 17], 1);
        edges_p[beg + p] = make_int2((e.x & 0x1FFFF) << 7, e.y);  // {row byte-offset, fp32 w}
    }
}

// ---------- phase 3: pull SpMM — EXACT proven r7 kernel (38.2 us/dispatch) ----------
template <int MODE>
__global__ __launch_bounds__(256) void spmm_pull(const __half* __restrict__ hprev,
                                                 const int2* __restrict__ nodeptr,
                                                 const int2* __restrict__ edges,
                                                 __half* __restrict__ hout,
                                                 float* __restrict__ out,
                                                 const float* __restrict__ X,
                                                 const __half* __restrict__ h1,
                                                 const __half* __restrict__ h2) {
    __shared__ int2 ebuf[4][WCAP];
    const int t    = threadIdx.x;
    const int wid  = t >> 6;
    const int lane = t & 63;
    const int half = lane >> 5;
    const int sub  = lane & 31;
    const unsigned loff = 4u * sub;           // per-lane byte offset within a row
    const int gw     = blockIdx.x * 4 + wid;
    const int nwaves = gridDim.x * 4;
    const char* hbase = (const char*)hprev;

    for (int node = gw; node < N_NODES; node += nwaves) {
        int2 np = nodeptr[node];
        const int beg = np.x, d = np.y;

        if (d <= WCAP) {
            const int dp = (d + 15) & ~15;    // padded count, <= 64
            if (lane < dp)
                ebuf[wid][lane] = (lane < d) ? edges[beg + lane] : make_int2(0, 0);
            float ax = 0.0f, ay = 0.0f;
            const int nb = dp >> 4;
            for (int bi = 0; bi < nb; ++bi) {
                const int base = bi * 16 + half;      // half 0: even slots, half 1: odd
                unsigned tv[8]; float w[8];
                #pragma unroll
                for (int k = 0; k < 8; ++k) {
                    int2 e = ebuf[wid][base + 2 * k]; // ds_read_b64 broadcast, imm offset
                    w[k]  = __int_as_float(e.y);
                    tv[k] = *(const unsigned*)(hbase + ((unsigned)e.x + loff));
                }
                #pragma unroll
                for (int k = 0; k < 8; ++k) {
                    float2 f = __half22float2(*(__half2*)&tv[k]);
                    ax += f.x * w[k];
                    ay += f.y * w[k];
                }
            }
            ax += __shfl_xor(ax, 32);
            ay += __shfl_xor(ay, 32);
            if (half == 0) {
                size_t bo = (size_t)node * 32 + sub;
                if (MODE == 2) {
                    float2 x  = ((const float2*)X)[bo];
                    float2 f1 = __half22float2(((const __half2*)h1)[bo]);
                    float2 f2 = __half22float2(((const __half2*)h2)[bo]);
                    ((float2*)out)[bo] = make_float2((x.x + f1.x + f2.x + ax) * 0.25f,
                                                     (x.y + f1.y + f2.y + ay) * 0.25f);
                } else {
                    ((__half2*)hout)[bo] = __floats2half2_rn(ax, ay);
                }
            }
        } else {
            // fallback (degree > 64: statistically never) — global path, same math
            const int end = beg + d;
            float ax = 0.0f, ay = 0.0f;
            for (int j = beg; j < end; j += 16) {
                #pragma unroll
                for (int k = 0; k < 8; ++k) {
                    int idx = j + 2 * k + half;
                    int2 e = (idx < end) ? edges[idx] : make_int2(0, 0);
                    float wk = __int_as_float(e.y);
                    unsigned tvk = *(const unsigned*)(hbase + ((unsigned)e.x + loff));
                    float2 f = __half22float2(*(__half2*)&tvk);
                    ax += f.x * wk;
                    ay += f.y * wk;
                }
            }
            ax += __shfl_xor(ax, 32);
            ay += __shfl_xor(ay, 32);
            if (half == 0) {
                size_t bo = (size_t)node * 32 + sub;
                if (MODE == 2) {
                    float2 x  = ((const float2*)X)[bo];
                    float2 f1 = __half22float2(((const __half2*)h1)[bo]);
                    float2 f2 = __half22float2(((const __half2*)h2)[bo]);
                    ((float2*)out)[bo] = make_float2((x.x + f1.x + f2.x + ax) * 0.25f,
                                                     (x.y + f1.y + f2.y + ay) * 0.25f);
                } else {
                    ((__half2*)hout)[bo] = __floats2half2_rn(ax, ay);
                }
            }
        }
    }
}

extern "C" void kernel_launch(void* const* d_in, const int* in_sizes, int n_in,
                              void* d_out, int out_size, void* d_ws, size_t ws_size,
                              hipStream_t stream) {
    const float* X   = (const float*)d_in[0];
    const int*   src = (const int*)  d_in[1];
    const int*   dst = (const int*)  d_in[2];
    const float* ew  = (const float*)d_in[3];
    float* out = (float*)d_out;

    const size_t feat = (size_t)N_NODES * D_FEAT;

    char* p = (char*)d_ws;
    __half* hA      = (__half*)p; p += feat * sizeof(__half);              // 12.8 MB
    __half* hB      = (__half*)p; p += feat * sizeof(__half);              // 12.8 MB
    __half* Xh      = (__half*)p; p += feat * sizeof(__half);              // 12.8 MB
    int2*  edges_p  = (int2*)p;   p += (size_t)NBUCK * CAP * sizeof(int2); // 19.2 MB (sorted in place)
    int2*  nodeptr  = (int2*)p;   p += (size_t)N_NODES * sizeof(int2);     // 0.8 MB
    int*   bcur     = (int*)p;    p += (size_t)NBUCK * 4;

    hipMemsetAsync(bcur, 0, (size_t)NBUCK * sizeof(int), stream);

    cvt_part   <<<CVT_BLOCKS, CVT_THREADS, 0, stream>>>(X, Xh, src, dst, ew, bcur, edges_p);
    sort_bucket<<<NBUCK, SORT_THREADS, 0, stream>>>(edges_p, bcur, nodeptr);

    spmm_pull<0><<<PULL_BLOCKS, 256, 0, stream>>>(Xh, nodeptr, edges_p, hA, out, X, hA, hB);
    spmm_pull<1><<<PULL_BLOCKS, 256, 0, stream>>>(hA, nodeptr, edges_p, hB, out, X, hA, hB);
    spmm_pull<2><<<PULL_BLOCKS, 256, 0, stream>>>(hB, nodeptr, edges_p, (__half*)nullptr, out, X, hA, hB);
}